// Round 1
// baseline (6577.157 us; speedup 1.0000x reference)
//
#include <hip/hip_runtime.h>
#include <hip/hip_bf16.h>

// ---------- types / helpers ----------
typedef __bf16 bf16x8 __attribute__((ext_vector_type(8)));
typedef float  f32x4  __attribute__((ext_vector_type(4)));

__device__ __forceinline__ unsigned short f2b(float f) {
    union { float f; unsigned u; } w; w.f = f;
    unsigned u = w.u + 0x7FFF + ((w.u >> 16) & 1);
    return (unsigned short)(u >> 16);
}
__device__ __forceinline__ float b2f(unsigned short s) {
    union { unsigned u; float f; } w; w.u = ((unsigned)s) << 16; return w.f;
}

#define GLD16(g, l) __builtin_amdgcn_global_load_lds( \
    (const __attribute__((address_space(1))) void*)(g), \
    (__attribute__((address_space(3))) void*)(l), 16, 0, 0)

// ---------- elementwise / conversion kernels ----------

// gather embedding rows, time-major: out[(t*64+b)*512 + e] = bf16(emb[tok[b][t]][e])
__global__ void k_gather(const float* __restrict__ emb, const int* __restrict__ tok,
                         unsigned short* __restrict__ out, int L, int ldtok) {
    long total = (long)L * 64 * 128;  // E/4 = 128
    for (long i = (long)blockIdx.x * blockDim.x + threadIdx.x; i < total;
         i += (long)gridDim.x * blockDim.x) {
        int  e4 = (int)(i & 127);
        long r  = i >> 7;
        int  t  = (int)(r >> 6), b = (int)(r & 63);
        int  tk = tok[b * ldtok + t];
        float4 v = *(const float4*)(emb + (long)tk * 512 + e4 * 4);
        ushort4 o; o.x = f2b(v.x); o.y = f2b(v.y); o.z = f2b(v.z); o.w = f2b(v.w);
        *(ushort4*)(out + r * 512 + e4 * 4) = o;
    }
}

// fp32 -> bf16 copy with optional gate-row reorder (out row n <- in row (n&3)*1024 + (n>>2))
__global__ void k_conv(const float* __restrict__ in, unsigned short* __restrict__ out,
                       long N_, int K_, int ldin, int col0, int ldout, int outcol0, int reorder) {
    long total = N_ * (K_ >> 2);
    int kq = K_ >> 2;
    for (long i = (long)blockIdx.x * blockDim.x + threadIdx.x; i < total;
         i += (long)gridDim.x * blockDim.x) {
        long n = i / kq;
        int  k4 = (int)(i - n * kq) * 4;
        long row = reorder ? (long)((n & 3) * 1024 + (n >> 2)) : n;
        float4 v = *(const float4*)(in + row * ldin + col0 + k4);
        ushort4 o; o.x = f2b(v.x); o.y = f2b(v.y); o.z = f2b(v.z); o.w = f2b(v.w);
        *(ushort4*)(out + n * ldout + outcol0 + k4) = o;
    }
}

// combined + reordered bias: out[n] = b1[row] + b2[row]
__global__ void k_bias(const float* __restrict__ b1, const float* __restrict__ b2,
                       float* __restrict__ out) {
    int n = blockIdx.x * blockDim.x + threadIdx.x;
    if (n < 4096) {
        int row = (n & 3) * 1024 + (n >> 2);
        out[n] = b1[row] + b2[row];
    }
}

// zero out[b][0][:] rows
__global__ void k_zero0(float* __restrict__ out) {
    long total = 64L * 8000;  // 32000/4 per row
    for (long i = (long)blockIdx.x * blockDim.x + threadIdx.x; i < total;
         i += (long)gridDim.x * blockDim.x) {
        int b = (int)(i / 8000), q = (int)(i % 8000);
        float4 z = {0.f, 0.f, 0.f, 0.f};
        *(float4*)(out + (long)b * 1024000 + q * 4) = z;
    }
}

// ---------- MFMA GEMM core: C(M,N) = A(M,K) @ B(N,K)^T, bf16 in, fp32 acc ----------
// m97 structure: BK=32, global_load_lds width 16, 2 barriers / K-step.
template<int BM, int BN, int WGM, int WGN, int FM, int FN>
__device__ __forceinline__ void gemm_core(
    const unsigned short* __restrict__ A, int lda,
    const unsigned short* __restrict__ B, int ldb,
    long m0, long n0, int K,
    unsigned short* As, unsigned short* Bs,
    f32x4 (&acc)[FM][FN])
{
    const int tid  = threadIdx.x;
    const int lane = tid & 63;
    const int wave = tid >> 6;
    const int wm = wave / WGN;
    const int wn = wave % WGN;
    const int srow = lane >> 2;        // row within 16-row staging chunk
    const int scol = (lane & 3) * 8;   // bf16 element offset within row
    const int frow = lane & 15;
    const int fcol = (lane >> 4) * 8;

    for (int k0 = 0; k0 < K; k0 += 32) {
        __syncthreads();
        for (int c = wave; c < BM / 16; c += 4) {
            const unsigned short* g = A + (m0 + c * 16 + srow) * (long)lda + k0 + scol;
            GLD16(g, As + c * 512);
        }
        for (int c = wave; c < BN / 16; c += 4) {
            const unsigned short* g = B + (n0 + c * 16 + srow) * (long)ldb + k0 + scol;
            GLD16(g, Bs + c * 512);
        }
        __syncthreads();
        bf16x8 af[FM], bfr[FN];
#pragma unroll
        for (int m = 0; m < FM; ++m)
            af[m] = *(const bf16x8*)(As + ((wm * FM + m) * 16 + frow) * 32 + fcol);
#pragma unroll
        for (int n = 0; n < FN; ++n)
            bfr[n] = *(const bf16x8*)(Bs + ((wn * FN + n) * 16 + frow) * 32 + fcol);
#pragma unroll
        for (int m = 0; m < FM; ++m)
#pragma unroll
            for (int n = 0; n < FN; ++n)
                acc[m][n] = __builtin_amdgcn_mfma_f32_16x16x32_bf16(af[m], bfr[n], acc[m][n], 0, 0, 0);
    }
}

// MODE 0: C[r][col] = acc + bias.  MODE 1 (fc): remap r=t*64+b -> out row b*32+t+1, guard r<Mreal.
template<int BM, int BN, int WGM, int WGN, int FM, int FN, int MODE>
__global__ __launch_bounds__(256) void k_gemm(
    const unsigned short* __restrict__ A, int lda,
    const unsigned short* __restrict__ B, int ldb,
    float* __restrict__ C, long ldc, const float* __restrict__ bias,
    int M, int N, int K, int Mreal)
{
    __shared__ __align__(16) unsigned short As[BM * 32];
    __shared__ __align__(16) unsigned short Bs[BN * 32];
    long m0 = (long)blockIdx.y * BM;
    long n0 = (long)blockIdx.x * BN;
    f32x4 acc[FM][FN] = {};
    gemm_core<BM, BN, WGM, WGN, FM, FN>(A, lda, B, ldb, m0, n0, K, As, Bs, acc);

    const int lane = threadIdx.x & 63;
    const int wave = threadIdx.x >> 6;
    const int wm = wave / WGN, wn = wave % WGN;
#pragma unroll
    for (int n = 0; n < FN; ++n) {
        long col = n0 + wn * FN * 16 + n * 16 + (lane & 15);
        float bv = bias ? bias[col] : 0.0f;
#pragma unroll
        for (int m = 0; m < FM; ++m) {
            int rl = wm * FM * 16 + m * 16 + (lane >> 4) * 4;
#pragma unroll
            for (int q = 0; q < 4; ++q) {
                long r = m0 + rl + q;
                float val = acc[m][n][q] + bv;
                if (MODE == 0) {
                    C[r * ldc + col] = val;
                } else {
                    if (r < Mreal) {
                        long orow = (r & 63) * 32 + (r >> 6) + 1;
                        C[orow * ldc + col] = val;
                    }
                }
            }
        }
    }
}

// ---------- fused recurrent step: gates GEMM + LSTM pointwise ----------
// A (64 x lda) bf16 holds [h | ctx]; W (4096 x ldb) bf16 gate-interleaved (n = j*4+g).
// gates = A@W^T + pre;  c,h update;  h written bf16 to h1 (stride 2048) and h2 (stride s2).
__global__ __launch_bounds__(256) void k_lstm(
    const unsigned short* __restrict__ A, int lda,
    const unsigned short* __restrict__ W, int ldb, int K,
    const float* __restrict__ pre, float* __restrict__ cb,
    unsigned short* __restrict__ h1, unsigned short* __restrict__ h2, long s2)
{
    constexpr int BM = 64, BN = 128, WGM = 1, WGN = 4, FM = 4, FN = 2;
    __shared__ __align__(16) unsigned short As[BM * 32];
    __shared__ __align__(16) unsigned short Bs[BN * 32];
    __shared__ float gs[64 * 128];
    long n0 = (long)blockIdx.x * BN;
    f32x4 acc[FM][FN] = {};
    gemm_core<BM, BN, WGM, WGN, FM, FN>(A, lda, W, ldb, 0, n0, K, As, Bs, acc);

    const int tid  = threadIdx.x;
    const int lane = tid & 63;
    const int wave = tid >> 6;
    const int wn = wave % WGN;
#pragma unroll
    for (int n = 0; n < FN; ++n) {
        int cl = wn * FN * 16 + n * 16 + (lane & 15);
#pragma unroll
        for (int m = 0; m < FM; ++m) {
            int rl = m * 16 + (lane >> 4) * 4;
#pragma unroll
            for (int q = 0; q < 4; ++q) gs[(rl + q) * 128 + cl] = acc[m][n][q];
        }
    }
    __syncthreads();
    for (int p = tid; p < 2048; p += 256) {
        int b = p >> 5, jl = p & 31;
        const float* pr = pre + (long)b * 4096 + n0 + jl * 4;
        float gi = gs[b * 128 + jl * 4 + 0] + pr[0];
        float gf = gs[b * 128 + jl * 4 + 1] + pr[1];
        float gg = gs[b * 128 + jl * 4 + 2] + pr[2];
        float go = gs[b * 128 + jl * 4 + 3] + pr[3];
        int j = (int)(n0 >> 2) + jl;
        float co = cb[b * 1024 + j];
        float i_ = 1.0f / (1.0f + expf(-gi));
        float f_ = 1.0f / (1.0f + expf(-gf));
        float g_ = tanhf(gg);
        float o_ = 1.0f / (1.0f + expf(-go));
        float cn = f_ * co + i_ * g_;
        float hn = o_ * tanhf(cn);
        cb[b * 1024 + j] = cn;
        unsigned short hb = f2b(hn);
        h1[(long)b * 2048 + j] = hb;
        h2[(long)b * s2 + j]   = hb;
    }
}

// ---------- attention: scores -> softmax -> context (fp32), per-b block ----------
__global__ __launch_bounds__(256) void k_attn(
    const float* __restrict__ q,             // 64 x 1024
    const float* __restrict__ proj,          // (b*64+s) x 1024 (attn_b folded in)
    const unsigned short* __restrict__ eo,   // enc_out bf16 (b*64+s) x 1024
    const float* __restrict__ v,             // 1024
    unsigned short* __restrict__ dcat,       // ctx -> dcat[b][1024+h]
    unsigned short* __restrict__ fccat)      // ctx -> fccat[t*64+b][1024+h]
{
    int b = blockIdx.x, tid = threadIdx.x;
    __shared__ float qv[1024], vv[1024], sc[64], al[64];
    for (int i = tid; i < 1024; i += 256) { qv[i] = q[b * 1024 + i]; vv[i] = v[i]; }
    __syncthreads();
    int s = tid >> 2, part = tid & 3;
    const float* pr = proj + ((long)b * 64 + s) * 1024 + part * 256;
    float acc = 0.f;
    for (int i = 0; i < 256; i += 4) {
        float4 p4 = *(const float4*)(pr + i);
        int h0 = part * 256 + i;
        acc += vv[h0 + 0] * tanhf(qv[h0 + 0] + p4.x);
        acc += vv[h0 + 1] * tanhf(qv[h0 + 1] + p4.y);
        acc += vv[h0 + 2] * tanhf(qv[h0 + 2] + p4.z);
        acc += vv[h0 + 3] * tanhf(qv[h0 + 3] + p4.w);
    }
    acc += __shfl_xor(acc, 1);
    acc += __shfl_xor(acc, 2);
    if (part == 0) sc[s] = acc;
    __syncthreads();
    if (tid < 64) {
        float x = sc[tid];
        float mx = x;
        for (int o = 32; o; o >>= 1) mx = fmaxf(mx, __shfl_xor(mx, o));
        float e = expf(x - mx);
        float sum = e;
        for (int o = 32; o; o >>= 1) sum += __shfl_xor(sum, o);
        al[tid] = e / sum;
    }
    __syncthreads();
    for (int hh = tid; hh < 1024; hh += 256) {
        float c = 0.f;
        const unsigned short* p = eo + (long)b * 65536 + hh;
        for (int s2 = 0; s2 < 64; ++s2) c += al[s2] * b2f(p[s2 * 1024]);
        unsigned short cbv = f2b(c);
        dcat[(long)b * 2048 + 1024 + hh]  = cbv;
        fccat[(long)b * 2048 + 1024 + hh] = cbv;
    }
}

// ---------- launch ----------
extern "C" void kernel_launch(void* const* d_in, const int* in_sizes, int n_in,
                              void* d_out, int out_size, void* d_ws, size_t ws_size,
                              hipStream_t stream) {
    const int*   src     = (const int*)d_in[0];
    const int*   tgt     = (const int*)d_in[1];
    const float* enc_emb = (const float*)d_in[2];
    const float* dec_emb = (const float*)d_in[3];
    const float* enc_Wih = (const float*)d_in[4];
    const float* enc_Whh = (const float*)d_in[5];
    const float* enc_bih = (const float*)d_in[6];
    const float* enc_bhh = (const float*)d_in[7];
    const float* dec_Wih = (const float*)d_in[8];
    const float* dec_Whh = (const float*)d_in[9];
    const float* dec_bih = (const float*)d_in[10];
    const float* dec_bhh = (const float*)d_in[11];
    const float* attn_W  = (const float*)d_in[12];
    const float* attn_b  = (const float*)d_in[13];
    const float* vvec    = (const float*)d_in[14];
    const float* fc_W    = (const float*)d_in[15];
    const float* fc_b    = (const float*)d_in[16];
    float* out = (float*)d_out;

    char* ws = (char*)d_ws;
    size_t off = 0;
    auto alloc = [&](size_t bytes) -> char* {
        off = (off + 255) & ~(size_t)255;
        char* p = ws + off; off += bytes; return p;
    };
    unsigned short* wX      = (unsigned short*)alloc(4096UL * 512 * 2);
    unsigned short* weWih   = (unsigned short*)alloc(4096UL * 512 * 2);
    unsigned short* weWhh   = (unsigned short*)alloc(4096UL * 1024 * 2);
    float*          ebias   = (float*)alloc(4096UL * 4);
    float*          pre_enc = (float*)alloc(4096UL * 4096 * 4);
    unsigned short* enc_out = (unsigned short*)alloc(4096UL * 1024 * 2);
    unsigned short* wWe     = (unsigned short*)alloc(1024UL * 1024 * 2);
    unsigned short* wWh     = (unsigned short*)alloc(1024UL * 1024 * 2);
    float*          proj    = (float*)alloc(4096UL * 1024 * 4);
    unsigned short* dcat0   = (unsigned short*)alloc(64UL * 2048 * 2);
    unsigned short* dcat1   = (unsigned short*)alloc(64UL * 2048 * 2);
    float*          cbuf    = (float*)alloc(64UL * 1024 * 4);
    float*          qbuf    = (float*)alloc(64UL * 1024 * 4);
    unsigned short* demb    = (unsigned short*)alloc(2048UL * 512 * 2);
    unsigned short* wDemb   = (unsigned short*)alloc(4096UL * 512 * 2);
    unsigned short* wCat    = (unsigned short*)alloc(4096UL * 2048 * 2);
    float*          dbias   = (float*)alloc(4096UL * 4);
    float*          pre_dec = (float*)alloc(2048UL * 4096 * 4);
    unsigned short* fccat   = (unsigned short*)alloc(2048UL * 2048 * 2);
    unsigned short* wFc     = (unsigned short*)alloc(32000UL * 2048 * 2);
    (void)ws_size; (void)in_sizes; (void)n_in; (void)out_size;

    hipMemsetAsync(dcat0, 0, 64UL * 2048 * 2, stream);
    hipMemsetAsync(dcat1, 0, 64UL * 2048 * 2, stream);
    hipMemsetAsync(cbuf,  0, 64UL * 1024 * 4, stream);
    k_zero0<<<512, 256, 0, stream>>>(out);

    k_gather<<<2048, 256, 0, stream>>>(enc_emb, src, wX, 64, 64);
    k_gather<<<1024, 256, 0, stream>>>(dec_emb, tgt, demb, 31, 32);
    k_conv<<<2048, 256, 0, stream>>>(enc_Wih, weWih, 4096, 512, 512, 0, 512, 0, 1);
    k_conv<<<2048, 256, 0, stream>>>(enc_Whh, weWhh, 4096, 1024, 1024, 0, 1024, 0, 1);
    k_conv<<<2048, 256, 0, stream>>>(dec_Wih, wDemb, 4096, 512, 1536, 0, 512, 0, 1);
    k_conv<<<2048, 256, 0, stream>>>(dec_Whh, wCat, 4096, 1024, 1024, 0, 2048, 0, 1);
    k_conv<<<2048, 256, 0, stream>>>(dec_Wih, wCat, 4096, 1024, 1536, 512, 2048, 1024, 1);
    k_conv<<<2048, 256, 0, stream>>>(attn_W, wWh, 1024, 1024, 2048, 0, 1024, 0, 0);
    k_conv<<<2048, 256, 0, stream>>>(attn_W, wWe, 1024, 1024, 2048, 1024, 1024, 0, 0);
    k_conv<<<4096, 256, 0, stream>>>(fc_W, wFc, 32000, 2048, 2048, 0, 2048, 0, 0);
    k_bias<<<16, 256, 0, stream>>>(enc_bih, enc_bhh, ebias);
    k_bias<<<16, 256, 0, stream>>>(dec_bih, dec_bhh, dbias);

    // pre-gates GEMMs
    k_gemm<128,128,2,2,4,4,0><<<dim3(32, 32), 256, 0, stream>>>(
        wX, 512, weWih, 512, pre_enc, 4096, ebias, 4096, 4096, 512, 4096);
    k_gemm<128,128,2,2,4,4,0><<<dim3(32, 16), 256, 0, stream>>>(
        demb, 512, wDemb, 512, pre_dec, 4096, dbias, 2048, 4096, 512, 2048);

    // encoder recurrence (ping-pong h buffers)
    for (int t = 0; t < 64; ++t) {
        const unsigned short* dr = (t & 1) ? dcat1 : dcat0;
        unsigned short*       dw = (t & 1) ? dcat0 : dcat1;
        k_lstm<<<32, 256, 0, stream>>>(dr, 2048, weWhh, 1024, 1024,
                                       pre_enc + (size_t)t * 64 * 4096, cbuf,
                                       dw, enc_out + (size_t)t * 1024, 65536);
    }
    // enc_proj (+attn_b)
    k_gemm<128,128,2,2,4,4,0><<<dim3(8, 32), 256, 0, stream>>>(
        enc_out, 1024, wWe, 1024, proj, 1024, attn_b, 4096, 1024, 1024, 4096);

    // decoder
    for (int t = 0; t < 31; ++t) {
        unsigned short* dr = (t & 1) ? dcat1 : dcat0;
        unsigned short* dw = (t & 1) ? dcat0 : dcat1;
        k_gemm<64,128,1,4,4,2,0><<<dim3(8, 1), 256, 0, stream>>>(
            dr, 2048, wWh, 1024, qbuf, 1024, nullptr, 64, 1024, 1024, 64);
        k_attn<<<64, 256, 0, stream>>>(qbuf, proj, enc_out, vvec,
                                       dr, fccat + (size_t)t * 64 * 2048);
        k_lstm<<<32, 256, 0, stream>>>(dr, 2048, wCat, 2048, 2048,
                                       pre_dec + (size_t)t * 64 * 4096, cbuf,
                                       dw, fccat + (size_t)t * 64 * 2048, 2048);
    }
    // batched fc GEMM -> out (remapped rows), rows b*32 zeroed by k_zero0
    k_gemm<128,128,2,2,4,4,1><<<dim3(250, 16), 256, 0, stream>>>(
        fccat, 2048, wFc, 2048, out, 32000, fc_b, 2048, 32000, 2048, 1984);
}

// Round 2
// 4659.766 us; speedup vs baseline: 1.4115x; 1.4115x over previous
//
#include <hip/hip_runtime.h>
#include <hip/hip_bf16.h>

// ---------- types / helpers ----------
typedef __bf16 bf16x8 __attribute__((ext_vector_type(8)));
typedef float  f32x4  __attribute__((ext_vector_type(4)));

__device__ __forceinline__ unsigned short f2b(float f) {
    union { float f; unsigned u; } w; w.f = f;
    unsigned u = w.u + 0x7FFF + ((w.u >> 16) & 1);
    return (unsigned short)(u >> 16);
}
__device__ __forceinline__ float b2f(unsigned short s) {
    union { unsigned u; float f; } w; w.u = ((unsigned)s) << 16; return w.f;
}

#define GLD16(g, l) __builtin_amdgcn_global_load_lds( \
    (const __attribute__((address_space(1))) void*)(g), \
    (__attribute__((address_space(3))) void*)(l), 16, 0, 0)

#define NBLK 64

// device-scope grid barrier (all NBLK blocks co-resident: 64 blocks <= 256 CUs)
__device__ __forceinline__ void gbar(int* cnt, int* gen, int target) {
    __syncthreads();
    if (threadIdx.x == 0) {
        __threadfence();   // release: block's global writes visible device-wide
        int v = __hip_atomic_fetch_add(cnt, 1, __ATOMIC_RELAXED, __HIP_MEMORY_SCOPE_AGENT);
        if (v == NBLK - 1) {
            __hip_atomic_store(cnt, 0, __ATOMIC_RELAXED, __HIP_MEMORY_SCOPE_AGENT);
            __hip_atomic_store(gen, target, __ATOMIC_RELEASE, __HIP_MEMORY_SCOPE_AGENT);
        } else {
            while (__hip_atomic_load(gen, __ATOMIC_RELAXED, __HIP_MEMORY_SCOPE_AGENT) < target)
                __builtin_amdgcn_s_sleep(2);
        }
        __threadfence();   // acquire: see other blocks' writes
    }
    __syncthreads();
}

// ---------- elementwise / conversion kernels ----------

__global__ void k_gather(const float* __restrict__ emb, const int* __restrict__ tok,
                         unsigned short* __restrict__ out, int L, int ldtok) {
    long total = (long)L * 64 * 128;
    for (long i = (long)blockIdx.x * blockDim.x + threadIdx.x; i < total;
         i += (long)gridDim.x * blockDim.x) {
        int  e4 = (int)(i & 127);
        long r  = i >> 7;
        int  t  = (int)(r >> 6), b = (int)(r & 63);
        int  tk = tok[b * ldtok + t];
        float4 v = *(const float4*)(emb + (long)tk * 512 + e4 * 4);
        ushort4 o; o.x = f2b(v.x); o.y = f2b(v.y); o.z = f2b(v.z); o.w = f2b(v.w);
        *(ushort4*)(out + r * 512 + e4 * 4) = o;
    }
}

__global__ void k_conv(const float* __restrict__ in, unsigned short* __restrict__ out,
                       long N_, int K_, int ldin, int col0, int ldout, int outcol0, int reorder) {
    long total = N_ * (K_ >> 2);
    int kq = K_ >> 2;
    for (long i = (long)blockIdx.x * blockDim.x + threadIdx.x; i < total;
         i += (long)gridDim.x * blockDim.x) {
        long n = i / kq;
        int  k4 = (int)(i - n * kq) * 4;
        long row = reorder ? (long)((n & 3) * 1024 + (n >> 2)) : n;
        float4 v = *(const float4*)(in + row * ldin + col0 + k4);
        ushort4 o; o.x = f2b(v.x); o.y = f2b(v.y); o.z = f2b(v.z); o.w = f2b(v.w);
        *(ushort4*)(out + n * ldout + outcol0 + k4) = o;
    }
}

__global__ void k_bias(const float* __restrict__ b1, const float* __restrict__ b2,
                       float* __restrict__ out) {
    int n = blockIdx.x * blockDim.x + threadIdx.x;
    if (n < 4096) {
        int row = (n & 3) * 1024 + (n >> 2);
        out[n] = b1[row] + b2[row];
    }
}

__global__ void k_zero0(float* __restrict__ out) {
    long total = 64L * 8000;
    for (long i = (long)blockIdx.x * blockDim.x + threadIdx.x; i < total;
         i += (long)gridDim.x * blockDim.x) {
        int b = (int)(i / 8000), q = (int)(i % 8000);
        float4 z = {0.f, 0.f, 0.f, 0.f};
        *(float4*)(out + (long)b * 1024000 + q * 4) = z;
    }
}

// ---------- big-GEMM core (prep + fc), unchanged from round 1 ----------
template<int BM, int BN, int WGM, int WGN, int FM, int FN>
__device__ __forceinline__ void gemm_core(
    const unsigned short* __restrict__ A, int lda,
    const unsigned short* __restrict__ B, int ldb,
    long m0, long n0, int K,
    unsigned short* As, unsigned short* Bs,
    f32x4 (&acc)[FM][FN])
{
    const int tid  = threadIdx.x;
    const int lane = tid & 63;
    const int wave = tid >> 6;
    const int wm = wave / WGN;
    const int wn = wave % WGN;
    const int srow = lane >> 2;
    const int scol = (lane & 3) * 8;
    const int frow = lane & 15;
    const int fcol = (lane >> 4) * 8;

    for (int k0 = 0; k0 < K; k0 += 32) {
        __syncthreads();
        for (int c = wave; c < BM / 16; c += 4) {
            const unsigned short* g = A + (m0 + c * 16 + srow) * (long)lda + k0 + scol;
            GLD16(g, As + c * 512);
        }
        for (int c = wave; c < BN / 16; c += 4) {
            const unsigned short* g = B + (n0 + c * 16 + srow) * (long)ldb + k0 + scol;
            GLD16(g, Bs + c * 512);
        }
        __syncthreads();
        bf16x8 af[FM], bfr[FN];
#pragma unroll
        for (int m = 0; m < FM; ++m)
            af[m] = *(const bf16x8*)(As + ((wm * FM + m) * 16 + frow) * 32 + fcol);
#pragma unroll
        for (int n = 0; n < FN; ++n)
            bfr[n] = *(const bf16x8*)(Bs + ((wn * FN + n) * 16 + frow) * 32 + fcol);
#pragma unroll
        for (int m = 0; m < FM; ++m)
#pragma unroll
            for (int n = 0; n < FN; ++n)
                acc[m][n] = __builtin_amdgcn_mfma_f32_16x16x32_bf16(af[m], bfr[n], acc[m][n], 0, 0, 0);
    }
}

template<int BM, int BN, int WGM, int WGN, int FM, int FN, int MODE>
__global__ __launch_bounds__(256) void k_gemm(
    const unsigned short* __restrict__ A, int lda,
    const unsigned short* __restrict__ B, int ldb,
    float* __restrict__ C, long ldc, const float* __restrict__ bias,
    int M, int N, int K, int Mreal)
{
    __shared__ __align__(16) unsigned short As[BM * 32];
    __shared__ __align__(16) unsigned short Bs[BN * 32];
    long m0 = (long)blockIdx.y * BM;
    long n0 = (long)blockIdx.x * BN;
    f32x4 acc[FM][FN] = {};
    gemm_core<BM, BN, WGM, WGN, FM, FN>(A, lda, B, ldb, m0, n0, K, As, Bs, acc);

    const int lane = threadIdx.x & 63;
    const int wave = threadIdx.x >> 6;
    const int wm = wave / WGN, wn = wave % WGN;
#pragma unroll
    for (int n = 0; n < FN; ++n) {
        long col = n0 + wn * FN * 16 + n * 16 + (lane & 15);
        float bv = bias ? bias[col] : 0.0f;
#pragma unroll
        for (int m = 0; m < FM; ++m) {
            int rl = wm * FM * 16 + m * 16 + (lane >> 4) * 4;
#pragma unroll
            for (int q = 0; q < 4; ++q) {
                long r = m0 + rl + q;
                float val = acc[m][n][q] + bv;
                if (MODE == 0) {
                    C[r * ldc + col] = val;
                } else {
                    if (r < Mreal) {
                        long orow = (r & 63) * 32 + (r >> 6) + 1;
                        C[orow * ldc + col] = val;
                    }
                }
            }
        }
    }
}

// ---------- persistent-step GEMM pieces (BK=64, dbuf prefetch, T2 swizzle) ----------

// stage an [nrows x 64] bf16 tile into LDS, linear dest + inverse-swizzled source
__device__ __forceinline__ void stage64(const unsigned short* gbase, long ldg,
                                        unsigned short* lds, int nrows) {
    const int lane = threadIdx.x & 63, wave = threadIdx.x >> 6;
    const int rr  = lane >> 3;           // row within 8-row chunk
    const int scb = ((lane & 7) << 4) ^ (rr << 4);  // swizzled source byte-col
    for (int c = wave; c < (nrows >> 3); c += 4) {
        const char* src = (const char*)(gbase + (long)(c * 8 + rr) * ldg) + scb;
        GLD16(src, lds + c * 512);
    }
}

// swizzled fragment read: row = rbase + (lane&15), k-slice kk (0/1 within BK=64)
__device__ __forceinline__ bf16x8 fragr(const unsigned short* lds, int rbase, int kk) {
    const int lane = threadIdx.x & 63;
    int r = rbase + (lane & 15);
    int byte = r * 128 + ((kk * 64 + ((lane >> 4) << 4)) ^ ((r & 7) << 4));
    return *(const bf16x8*)((const char*)lds + byte);
}

// 64x64 tile, wave w owns cols w*16..w*16+15; acc[m] = rows m*16..+15
template<int KT>
__device__ __forceinline__ void pgemm64(const unsigned short* A, long lda,
                                        const unsigned short* B, long ldb,
                                        unsigned short (*As)[4096], unsigned short (*Bs)[4096],
                                        f32x4 (&acc)[4]) {
    const int wave = threadIdx.x >> 6;
    constexpr int NT = KT / 64;
    stage64(A, lda, As[0], 64);
    stage64(B, ldb, Bs[0], 64);
    __syncthreads();
    for (int kt = 0; kt < NT; ++kt) {
        int par = kt & 1;
        if (kt + 1 < NT) {
            stage64(A + (kt + 1) * 64, lda, As[par ^ 1], 64);
            stage64(B + (kt + 1) * 64, ldb, Bs[par ^ 1], 64);
        }
#pragma unroll
        for (int kk = 0; kk < 2; ++kk) {
            bf16x8 bfv = fragr(Bs[par], wave * 16, kk);
#pragma unroll
            for (int m = 0; m < 4; ++m) {
                bf16x8 afv = fragr(As[par], m * 16, kk);
                acc[m] = __builtin_amdgcn_mfma_f32_16x16x32_bf16(afv, bfv, acc[m], 0, 0, 0);
            }
        }
        __syncthreads();
    }
}

// 64x16 tile, wave w owns rows w*16..+15, single 16-col block
template<int KT>
__device__ __forceinline__ void pgemm16(const unsigned short* A, long lda,
                                        const unsigned short* B, long ldb,
                                        unsigned short (*As)[4096], unsigned short (*Bs)[4096],
                                        f32x4& acc) {
    const int wave = threadIdx.x >> 6;
    constexpr int NT = KT / 64;
    stage64(A, lda, As[0], 64);
    stage64(B, ldb, Bs[0], 16);
    __syncthreads();
    for (int kt = 0; kt < NT; ++kt) {
        int par = kt & 1;
        if (kt + 1 < NT) {
            stage64(A + (kt + 1) * 64, lda, As[par ^ 1], 64);
            stage64(B + (kt + 1) * 64, ldb, Bs[par ^ 1], 16);
        }
#pragma unroll
        for (int kk = 0; kk < 2; ++kk) {
            bf16x8 afv = fragr(As[par], wave * 16, kk);
            bf16x8 bfv = fragr(Bs[par], 0, kk);
            acc = __builtin_amdgcn_mfma_f32_16x16x32_bf16(afv, bfv, acc, 0, 0, 0);
        }
        __syncthreads();
    }
}

// ---------- persistent encoder: 64 LSTM steps, 1 grid-barrier each ----------
__global__ __launch_bounds__(256, 1) void k_enc(
    const unsigned short* __restrict__ W,    // weWhh 4096x1024 (gate-interleaved rows)
    const float* __restrict__ pre,           // [64][64][4096]
    unsigned short* __restrict__ h0,         // 64x1024 bf16 (zeroed)
    unsigned short* __restrict__ h1,
    unsigned short* __restrict__ enc_out,    // rows (b*64+t) x 1024
    unsigned short* __restrict__ hf,         // dcat0: h_f at stride 2048
    float* __restrict__ cspill,              // 64x1024 f32
    int* cnt, int* gen)
{
    __shared__ __align__(16) unsigned short As[2][4096];
    __shared__ __align__(16) unsigned short Bs[2][4096];
    __shared__ float gs[64 * 64];
    __shared__ float cs[64 * 16];
    const int blk = blockIdx.x, tid = threadIdx.x;
    const int n0 = blk * 64, j0 = blk * 16;
    const int lane = tid & 63, wave = tid >> 6;
    for (int i = tid; i < 1024; i += 256) cs[i] = 0.f;
    __syncthreads();
    int bt = 0;
    for (int t = 0; t < 64; ++t) {
        const unsigned short* A = (t & 1) ? h1 : h0;
        unsigned short* hw = (t & 1) ? h0 : h1;
        f32x4 acc[4] = {};
        pgemm64<1024>(A, 1024, W + (long)n0 * 1024, 1024, As, Bs, acc);
#pragma unroll
        for (int m = 0; m < 4; ++m)
#pragma unroll
            for (int q = 0; q < 4; ++q)
                gs[(m * 16 + (lane >> 4) * 4 + q) * 64 + wave * 16 + (lane & 15)] = acc[m][q];
        __syncthreads();
        const float* pt = pre + (long)t * 64 * 4096;
#pragma unroll
        for (int i = 0; i < 4; ++i) {
            int pp = tid + i * 256;
            int b = pp >> 4, jl = pp & 15;
            float4 g4 = *(const float4*)(gs + b * 64 + jl * 4);
            float4 p4 = *(const float4*)(pt + (long)b * 4096 + n0 + jl * 4);
            float gi = g4.x + p4.x, gf = g4.y + p4.y, gg = g4.z + p4.z, go = g4.w + p4.w;
            float co = cs[b * 16 + jl];
            float i_ = 1.0f / (1.0f + expf(-gi));
            float f_ = 1.0f / (1.0f + expf(-gf));
            float g_ = tanhf(gg);
            float o_ = 1.0f / (1.0f + expf(-go));
            float cn = f_ * co + i_ * g_;
            float hn = o_ * tanhf(cn);
            cs[b * 16 + jl] = cn;
            unsigned short hb = f2b(hn);
            hw[(long)b * 1024 + j0 + jl] = hb;
            enc_out[((long)b * 64 + t) * 1024 + j0 + jl] = hb;
            if (t == 63) {
                hf[(long)b * 2048 + j0 + jl] = hb;
                cspill[(long)b * 1024 + j0 + jl] = cn;
            }
        }
        gbar(cnt, gen, ++bt);
    }
}

// ---------- persistent decoder: 31 steps x (q-GEMM | attention | gates+LSTM) ----------
__global__ __launch_bounds__(256, 1) void k_dec(
    const unsigned short* __restrict__ Wh,   // 1024x1024
    const unsigned short* __restrict__ Wc,   // 4096x2048 (gate-interleaved rows)
    const float* __restrict__ pre,           // [31][64][4096]
    const float* __restrict__ proj,          // (b*64+s) x 1024 (attn_b folded)
    const unsigned short* __restrict__ eo,   // enc_out bf16
    const float* __restrict__ v,             // 1024
    const float* __restrict__ cspill,
    unsigned short* __restrict__ dcat0, unsigned short* __restrict__ dcat1,
    float* __restrict__ qbuf,                // 64x1024 f32
    unsigned short* __restrict__ fccat,      // (t*64+b) x 2048
    int* cnt, int* gen)
{
    __shared__ __align__(16) unsigned short As[2][4096];
    __shared__ __align__(16) unsigned short Bs[2][4096];
    __shared__ float gs[64 * 64];
    __shared__ float cs[64 * 16];
    __shared__ float qv[1024], vv[1024], sc[64], al[64];
    const int blk = blockIdx.x, tid = threadIdx.x;
    const int n0 = blk * 64, j0 = blk * 16, q0 = blk * 16;
    const int lane = tid & 63, wave = tid >> 6;
    for (int i = tid; i < 1024; i += 256) {
        cs[i] = cspill[(long)(i >> 4) * 1024 + j0 + (i & 15)];
        vv[i] = v[i];
    }
    __syncthreads();
    int bt = 0;
    for (int t = 0; t < 31; ++t) {
        unsigned short* dr = (t & 1) ? dcat1 : dcat0;
        unsigned short* dw = (t & 1) ? dcat0 : dcat1;
        // ---- phase 1: q slice = h @ Wh[q0..q0+15]^T
        {
            f32x4 qa = {};
            pgemm16<1024>(dr, 2048, Wh + (long)q0 * 1024, 1024, As, Bs, qa);
            int row = wave * 16 + (lane >> 4) * 4;
            int col = q0 + (lane & 15);
#pragma unroll
            for (int q = 0; q < 4; ++q) qbuf[(long)(row + q) * 1024 + col] = qa[q];
        }
        gbar(cnt, gen, ++bt);
        // ---- phase 2: attention for batch row b = blk
        {
            const int b = blk;
            for (int i = tid; i < 1024; i += 256) qv[i] = qbuf[(long)b * 1024 + i];
            __syncthreads();
            int s = tid >> 2, part = tid & 3;
            const float* pr = proj + ((long)b * 64 + s) * 1024 + part * 256;
            float a_ = 0.f;
            for (int i = 0; i < 256; i += 4) {
                float4 p4 = *(const float4*)(pr + i);
                int hh = part * 256 + i;
                a_ += vv[hh + 0] * tanhf(qv[hh + 0] + p4.x);
                a_ += vv[hh + 1] * tanhf(qv[hh + 1] + p4.y);
                a_ += vv[hh + 2] * tanhf(qv[hh + 2] + p4.z);
                a_ += vv[hh + 3] * tanhf(qv[hh + 3] + p4.w);
            }
            a_ += __shfl_xor(a_, 1);
            a_ += __shfl_xor(a_, 2);
            if (part == 0) sc[s] = a_;
            __syncthreads();
            if (tid < 64) {
                float x = sc[tid], mx = x;
                for (int o = 32; o; o >>= 1) mx = fmaxf(mx, __shfl_xor(mx, o));
                float e = expf(x - mx), su = e;
                for (int o = 32; o; o >>= 1) su += __shfl_xor(su, o);
                al[tid] = e / su;
            }
            __syncthreads();
            for (int hh = tid; hh < 1024; hh += 256) {
                float c = 0.f;
                const unsigned short* p = eo + (long)b * 65536 + hh;
                for (int s2 = 0; s2 < 64; ++s2) c += al[s2] * b2f(p[s2 * 1024]);
                unsigned short cb2 = f2b(c);
                dr[(long)b * 2048 + 1024 + hh] = cb2;
                fccat[((long)t * 64 + b) * 2048 + 1024 + hh] = cb2;
            }
        }
        gbar(cnt, gen, ++bt);
        // ---- phase 3: gates = [h|ctx] @ Wc^T + pre; LSTM pointwise
        {
            f32x4 acc[4] = {};
            pgemm64<2048>(dr, 2048, Wc + (long)n0 * 2048, 2048, As, Bs, acc);
#pragma unroll
            for (int m = 0; m < 4; ++m)
#pragma unroll
                for (int q = 0; q < 4; ++q)
                    gs[(m * 16 + (lane >> 4) * 4 + q) * 64 + wave * 16 + (lane & 15)] = acc[m][q];
            __syncthreads();
            const float* pt = pre + (long)t * 64 * 4096;
#pragma unroll
            for (int i = 0; i < 4; ++i) {
                int pp = tid + i * 256;
                int b = pp >> 4, jl = pp & 15;
                float4 g4 = *(const float4*)(gs + b * 64 + jl * 4);
                float4 p4 = *(const float4*)(pt + (long)b * 4096 + n0 + jl * 4);
                float gi = g4.x + p4.x, gf = g4.y + p4.y, gg = g4.z + p4.z, go = g4.w + p4.w;
                float co = cs[b * 16 + jl];
                float i_ = 1.0f / (1.0f + expf(-gi));
                float f_ = 1.0f / (1.0f + expf(-gf));
                float g_ = tanhf(gg);
                float o_ = 1.0f / (1.0f + expf(-go));
                float cn = f_ * co + i_ * g_;
                float hn = o_ * tanhf(cn);
                cs[b * 16 + jl] = cn;
                unsigned short hb = f2b(hn);
                dw[(long)b * 2048 + j0 + jl] = hb;
                fccat[((long)t * 64 + b) * 2048 + j0 + jl] = hb;
            }
        }
        gbar(cnt, gen, ++bt);
    }
}

// ---------- launch ----------
extern "C" void kernel_launch(void* const* d_in, const int* in_sizes, int n_in,
                              void* d_out, int out_size, void* d_ws, size_t ws_size,
                              hipStream_t stream) {
    const int*   src     = (const int*)d_in[0];
    const int*   tgt     = (const int*)d_in[1];
    const float* enc_emb = (const float*)d_in[2];
    const float* dec_emb = (const float*)d_in[3];
    const float* enc_Wih = (const float*)d_in[4];
    const float* enc_Whh = (const float*)d_in[5];
    const float* enc_bih = (const float*)d_in[6];
    const float* enc_bhh = (const float*)d_in[7];
    const float* dec_Wih = (const float*)d_in[8];
    const float* dec_Whh = (const float*)d_in[9];
    const float* dec_bih = (const float*)d_in[10];
    const float* dec_bhh = (const float*)d_in[11];
    const float* attn_W  = (const float*)d_in[12];
    const float* attn_b  = (const float*)d_in[13];
    const float* vvec    = (const float*)d_in[14];
    const float* fc_W    = (const float*)d_in[15];
    const float* fc_b    = (const float*)d_in[16];
    float* out = (float*)d_out;

    char* ws = (char*)d_ws;
    size_t off = 0;
    auto alloc = [&](size_t bytes) -> char* {
        off = (off + 255) & ~(size_t)255;
        char* p = ws + off; off += bytes; return p;
    };
    unsigned short* wX      = (unsigned short*)alloc(4096UL * 512 * 2);
    unsigned short* weWih   = (unsigned short*)alloc(4096UL * 512 * 2);
    unsigned short* weWhh   = (unsigned short*)alloc(4096UL * 1024 * 2);
    float*          ebias   = (float*)alloc(4096UL * 4);
    float*          pre_enc = (float*)alloc(4096UL * 4096 * 4);
    unsigned short* enc_out = (unsigned short*)alloc(4096UL * 1024 * 2);
    unsigned short* wWe     = (unsigned short*)alloc(1024UL * 1024 * 2);
    unsigned short* wWh     = (unsigned short*)alloc(1024UL * 1024 * 2);
    float*          proj    = (float*)alloc(4096UL * 1024 * 4);
    unsigned short* dcat0   = (unsigned short*)alloc(64UL * 2048 * 2);
    unsigned short* dcat1   = (unsigned short*)alloc(64UL * 2048 * 2);
    float*          cbuf    = (float*)alloc(64UL * 1024 * 4);
    float*          qbuf    = (float*)alloc(64UL * 1024 * 4);
    unsigned short* demb    = (unsigned short*)alloc(2048UL * 512 * 2);
    unsigned short* wDemb   = (unsigned short*)alloc(4096UL * 512 * 2);
    unsigned short* wCat    = (unsigned short*)alloc(4096UL * 2048 * 2);
    float*          dbias   = (float*)alloc(4096UL * 4);
    float*          pre_dec = (float*)alloc(2048UL * 4096 * 4);
    unsigned short* fccat   = (unsigned short*)alloc(2048UL * 2048 * 2);
    unsigned short* wFc     = (unsigned short*)alloc(32000UL * 2048 * 2);
    unsigned short* hbuf0   = (unsigned short*)alloc(64UL * 1024 * 2);
    unsigned short* hbuf1   = (unsigned short*)alloc(64UL * 1024 * 2);
    int*            bar     = (int*)alloc(256);
    (void)ws_size; (void)in_sizes; (void)n_in; (void)out_size;

    hipMemsetAsync(bar, 0, 256, stream);
    hipMemsetAsync(hbuf0, 0, 64UL * 1024 * 2, stream);
    k_zero0<<<512, 256, 0, stream>>>(out);

    k_gather<<<2048, 256, 0, stream>>>(enc_emb, src, wX, 64, 64);
    k_gather<<<1024, 256, 0, stream>>>(dec_emb, tgt, demb, 31, 32);
    k_conv<<<2048, 256, 0, stream>>>(enc_Wih, weWih, 4096, 512, 512, 0, 512, 0, 1);
    k_conv<<<2048, 256, 0, stream>>>(enc_Whh, weWhh, 4096, 1024, 1024, 0, 1024, 0, 1);
    k_conv<<<2048, 256, 0, stream>>>(dec_Wih, wDemb, 4096, 512, 1536, 0, 512, 0, 1);
    k_conv<<<2048, 256, 0, stream>>>(dec_Whh, wCat, 4096, 1024, 1024, 0, 2048, 0, 1);
    k_conv<<<2048, 256, 0, stream>>>(dec_Wih, wCat, 4096, 1024, 1536, 512, 2048, 1024, 1);
    k_conv<<<2048, 256, 0, stream>>>(attn_W, wWh, 1024, 1024, 2048, 0, 1024, 0, 0);
    k_conv<<<2048, 256, 0, stream>>>(attn_W, wWe, 1024, 1024, 2048, 1024, 1024, 0, 0);
    k_conv<<<4096, 256, 0, stream>>>(fc_W, wFc, 32000, 2048, 2048, 0, 2048, 0, 0);
    k_bias<<<16, 256, 0, stream>>>(enc_bih, enc_bhh, ebias);
    k_bias<<<16, 256, 0, stream>>>(dec_bih, dec_bhh, dbias);

    // pre-gates GEMMs
    k_gemm<128,128,2,2,4,4,0><<<dim3(32, 32), 256, 0, stream>>>(
        wX, 512, weWih, 512, pre_enc, 4096, ebias, 4096, 4096, 512, 4096);
    k_gemm<128,128,2,2,4,4,0><<<dim3(32, 16), 256, 0, stream>>>(
        demb, 512, wDemb, 512, pre_dec, 4096, dbias, 2048, 4096, 512, 2048);

    // persistent encoder (64 steps)
    k_enc<<<NBLK, 256, 0, stream>>>(weWhh, pre_enc, hbuf0, hbuf1, enc_out,
                                    dcat0, cbuf, bar + 0, bar + 1);

    // enc_proj (+attn_b)
    k_gemm<128,128,2,2,4,4,0><<<dim3(8, 32), 256, 0, stream>>>(
        enc_out, 1024, wWe, 1024, proj, 1024, attn_b, 4096, 1024, 1024, 4096);

    // persistent decoder (31 steps x 3 phases)
    k_dec<<<NBLK, 256, 0, stream>>>(wWh, wCat, pre_dec, proj, enc_out, vvec, cbuf,
                                    dcat0, dcat1, qbuf, fccat, bar + 2, bar + 3);

    // batched fc GEMM -> out (remapped rows), rows b*32 zeroed by k_zero0
    k_gemm<128,128,2,2,4,4,1><<<dim3(250, 16), 256, 0, stream>>>(
        fccat, 2048, wFc, 2048, out, 32000, fc_b, 2048, 32000, 2048, 1984);
}